// Round 1
// baseline (1378.145 us; speedup 1.0000x reference)
//
#include <hip/hip_runtime.h>
#include <hip/hip_bf16.h>
#include <stdint.h>

typedef unsigned short u16;
typedef __attribute__((ext_vector_type(4))) float f32x4;
typedef __attribute__((ext_vector_type(4))) float float4v;
typedef __attribute__((ext_vector_type(8))) __bf16 bf16x8;

// ---------- helpers ----------
__device__ __forceinline__ u16 f2bf_rne(float f) {
  union { float f; uint32_t u; } v; v.f = f;
  uint32_t u = v.u;
  uint32_t r = (u + 0x7fffu + ((u >> 16) & 1u)) >> 16;
  return (u16)r;
}

__device__ __forceinline__ void gld_lds16(const void* g, void* l) {
  __builtin_amdgcn_global_load_lds((const __attribute__((address_space(1))) void*)g,
                                   (__attribute__((address_space(3))) void*)l,
                                   16, 0, 0);
}

// ---------- kernel 0: x (fp32) -> Xb (bf16), 8 elems/thread ----------
__global__ __launch_bounds__(256) void k_cvt_x(const float* __restrict__ x, u16* __restrict__ xb) {
  const int t = blockIdx.x * 256 + threadIdx.x;       // one per 8 elements
  const f32x4* xp = (const f32x4*)x;
  f32x4 a = xp[2 * (size_t)t];
  f32x4 b = xp[2 * (size_t)t + 1];
  uint32_t w0 = (uint32_t)f2bf_rne(a[0]) | ((uint32_t)f2bf_rne(a[1]) << 16);
  uint32_t w1 = (uint32_t)f2bf_rne(a[2]) | ((uint32_t)f2bf_rne(a[3]) << 16);
  uint32_t w2 = (uint32_t)f2bf_rne(b[0]) | ((uint32_t)f2bf_rne(b[1]) << 16);
  uint32_t w3 = (uint32_t)f2bf_rne(b[2]) | ((uint32_t)f2bf_rne(b[3]) << 16);
  ((uint4*)xb)[t] = make_uint4(w0, w1, w2, w3);
}

// ---------- kernel 1: T1[64][4096] = core0(64x64) @ core1(64x4096) ----------
__global__ __launch_bounds__(256) void k_t1(const float* __restrict__ c0, const float* __restrict__ c1,
                                            float* __restrict__ T1) {
  const int col = blockIdx.x * 256 + threadIdx.x;  // [0,4096)
  const int row = blockIdx.y;                      // [0,64)
  float acc = 0.f;
#pragma unroll 16
  for (int r = 0; r < 64; ++r) acc += c0[row * 64 + r] * c1[(size_t)r * 4096 + col];
  T1[(size_t)row * 4096 + col] = acc;
}

// ---------- kernel 2: T2[4096][4096] = T1r(4096x64) @ core2(64x4096) ----------
// T1 reshaped: row' = i1o1*64+i2o2, col' = r2 (same linear layout).
__global__ __launch_bounds__(256) void k_t2(const float* __restrict__ T1, const float* __restrict__ c2,
                                            float* __restrict__ T2) {
  __shared__ float t1s[16][64];
  const int tid = threadIdx.x;
  const int rowbase = blockIdx.y * 16;
  for (int idx = tid; idx < 1024; idx += 256)
    t1s[idx >> 6][idx & 63] = T1[(size_t)(rowbase + (idx >> 6)) * 64 + (idx & 63)];
  __syncthreads();
  const int col = blockIdx.x * 256 + tid;  // [0,4096)
  float acc[16];
#pragma unroll
  for (int j = 0; j < 16; ++j) acc[j] = 0.f;
  for (int r = 0; r < 64; ++r) {
    float b = c2[(size_t)r * 4096 + col];
#pragma unroll
    for (int j = 0; j < 16; ++j) acc[j] += t1s[j][r] * b;
  }
#pragma unroll
  for (int j = 0; j < 16; ++j) T2[(size_t)(rowbase + j) * 4096 + col] = acc[j];
}

// ---------- kernel 3: Wb[o][i] (bf16) = sum_r3 T2[row12][i3o3*64+r3] * core3[r3][i4o4], fused permute ----------
__global__ __launch_bounds__(256) void k_w(const float* __restrict__ T2, const float* __restrict__ c3,
                                           u16* __restrict__ Wb) {
  const int tid = threadIdx.x;
  const int wave = tid >> 6, lane = tid & 63;
  const int seg = blockIdx.x * 4 + wave;     // [0, 262144)
  const int row12 = seg >> 6;                // [0,4096) = (i1*8+o1)*64 + (i2*8+o2)
  const int i3o3 = seg & 63;
  const float* s = T2 + (size_t)row12 * 4096 + i3o3 * 64;
  float acc = 0.f;
#pragma unroll 16
  for (int r = 0; r < 64; ++r) acc += s[r] * c3[r * 64 + lane];   // lane = i4*8+o4
  const int i1o1 = row12 >> 6, i2o2 = row12 & 63;
  const int o = ((i1o1 & 7) << 9) | ((i2o2 & 7) << 6) | ((i3o3 & 7) << 3) | (lane & 7);
  const int i = ((i1o1 >> 3) << 9) | ((i2o2 >> 3) << 6) | ((i3o3 >> 3) << 3) | (lane >> 3);
  Wb[(size_t)o * 4096 + i] = f2bf_rne(acc);
}

// ---------- kernel 4: out(16384x4096) = Xb(16384x4096) @ Wb(4096x4096)^T + bias ----------
// m97 structure: 128x128 tile, 4 waves (2x2 of 64x64), BK=32, 16x16x32 bf16 MFMA,
// global_load_lds width=16 staging, 2 barriers per K-step.
__global__ __launch_bounds__(256) void k_gemm(const u16* __restrict__ Xb, const u16* __restrict__ Wb,
                                              const float* __restrict__ bias, float* __restrict__ out) {
  __shared__ alignas(16) u16 As[128][32];
  __shared__ alignas(16) u16 Bs[128][32];
  const int tid = threadIdx.x;
  const int w = tid >> 6, lane = tid & 63;
  const int bm = blockIdx.x;  // 0..127
  const int bn = blockIdx.y;  // 0..31
  const size_t K = 4096;

  // staging geometry: chunk c covers tile rows [c*16, c*16+16), 1024B per chunk (wave-uniform LDS base)
  const int srow = lane >> 2;          // row within chunk
  const int scol = (lane & 3) * 8;     // elem col within row
  const int ca0 = w * 2, ca1 = w * 2 + 1;
  const u16* ga0 = Xb + (size_t)(bm * 128 + ca0 * 16 + srow) * K + scol;
  const u16* ga1 = Xb + (size_t)(bm * 128 + ca1 * 16 + srow) * K + scol;
  const u16* gb0 = Wb + (size_t)(bn * 128 + ca0 * 16 + srow) * K + scol;
  const u16* gb1 = Wb + (size_t)(bn * 128 + ca1 * 16 + srow) * K + scol;
  u16* la0 = &As[ca0 * 16][0];
  u16* la1 = &As[ca1 * 16][0];
  u16* lb0 = &Bs[ca0 * 16][0];
  u16* lb1 = &Bs[ca1 * 16][0];

  // MFMA fragment geometry
  const int wr = w >> 1, wc = w & 1;
  const int lrow = lane & 15;
  const int lko = (lane >> 4) * 8;

  f32x4 acc[4][4];
#pragma unroll
  for (int m = 0; m < 4; ++m)
#pragma unroll
    for (int n = 0; n < 4; ++n) acc[m][n] = (f32x4){0.f, 0.f, 0.f, 0.f};

  for (int kt = 0; kt < 4096; kt += 32) {
    gld_lds16(ga0 + kt, la0);
    gld_lds16(ga1 + kt, la1);
    gld_lds16(gb0 + kt, lb0);
    gld_lds16(gb1 + kt, lb1);
    __syncthreads();
    bf16x8 a[4], b[4];
#pragma unroll
    for (int m = 0; m < 4; ++m) a[m] = *(const bf16x8*)&As[wr * 64 + m * 16 + lrow][lko];
#pragma unroll
    for (int n = 0; n < 4; ++n) b[n] = *(const bf16x8*)&Bs[wc * 64 + n * 16 + lrow][lko];
#pragma unroll
    for (int m = 0; m < 4; ++m)
#pragma unroll
      for (int n = 0; n < 4; ++n)
        acc[m][n] = __builtin_amdgcn_mfma_f32_16x16x32_bf16(a[m], b[n], acc[m][n], 0, 0, 0);
    __syncthreads();
  }

  // epilogue: C/D mapping col=lane&15, row=(lane>>4)*4+j (m89-verified)
  const int orow_base = bm * 128 + wr * 64 + (lane >> 4) * 4;
  const int ocol_base = bn * 128 + wc * 64 + (lane & 15);
#pragma unroll
  for (int n = 0; n < 4; ++n) {
    const int oc = ocol_base + n * 16;
    const float bv = bias[oc];
#pragma unroll
    for (int m = 0; m < 4; ++m) {
      const int orb = orow_base + m * 16;
#pragma unroll
      for (int j = 0; j < 4; ++j)
        out[(size_t)(orb + j) * 4096 + oc] = acc[m][n][j] + bv;
    }
  }
}

extern "C" void kernel_launch(void* const* d_in, const int* in_sizes, int n_in,
                              void* d_out, int out_size, void* d_ws, size_t ws_size,
                              hipStream_t stream) {
  const float* x    = (const float*)d_in[0];
  const float* c0   = (const float*)d_in[1];
  const float* c1   = (const float*)d_in[2];
  const float* c2   = (const float*)d_in[3];
  const float* c3   = (const float*)d_in[4];
  const float* bias = (const float*)d_in[5];
  float* out = (float*)d_out;

  char* ws = (char*)d_ws;
  float* T1 = (float*)ws;                                        //  1 MiB: 64*4096 f32
  float* T2 = (float*)(ws + (1u << 20));                         // 64 MiB: 4096*4096 f32
  u16*   Wb = (u16*)(ws + (1u << 20) + (64u << 20));             // 32 MiB: 4096*4096 bf16
  u16*   Xb = (u16*)(ws + (1u << 20) + (64u << 20) + (32u << 20)); // 128 MiB: 16384*4096 bf16

  hipLaunchKernelGGL(k_cvt_x, dim3(32768), dim3(256), 0, stream, x, Xb);
  hipLaunchKernelGGL(k_t1,    dim3(16, 64), dim3(256), 0, stream, c0, c1, T1);
  hipLaunchKernelGGL(k_t2,    dim3(16, 256), dim3(256), 0, stream, T1, c2, T2);
  hipLaunchKernelGGL(k_w,     dim3(65536), dim3(256), 0, stream, T2, c3, Wb);
  hipLaunchKernelGGL(k_gemm,  dim3(128, 32), dim3(256), 0, stream, Xb, Wb, bias, out);
}

// Round 5
// 1064.701 us; speedup vs baseline: 1.2944x; 1.2944x over previous
//
#include <hip/hip_runtime.h>
#include <hip/hip_bf16.h>
#include <stdint.h>

typedef unsigned short u16;
typedef __attribute__((ext_vector_type(4))) float f32x4;
typedef __attribute__((ext_vector_type(8))) __bf16 bf16x8;

#define K_DIM 4096

// ---------- helpers ----------
__device__ __forceinline__ u16 f2bf_rne(float f) {
  union { float f; uint32_t u; } v; v.f = f;
  uint32_t u = v.u;
  return (u16)((u + 0x7fffu + ((u >> 16) & 1u)) >> 16);
}

__device__ __forceinline__ void gld_lds16(const u16* g, u16* l) {
  __builtin_amdgcn_global_load_lds((const __attribute__((address_space(1))) void*)g,
                                   (__attribute__((address_space(3))) void*)l,
                                   16, 0, 0);
}

// ---------- kernel 0: x (fp32) -> Xb (bf16), unit-stride, grid-stride ----------
__global__ __launch_bounds__(256) void k_cvt_x(const float* __restrict__ x, u16* __restrict__ xb, int n4) {
  const int stride = gridDim.x * 256;
  for (int i = blockIdx.x * 256 + threadIdx.x; i < n4; i += stride) {
    f32x4 a = ((const f32x4*)x)[i];
    uint2 o;
    o.x = (uint32_t)f2bf_rne(a[0]) | ((uint32_t)f2bf_rne(a[1]) << 16);
    o.y = (uint32_t)f2bf_rne(a[2]) | ((uint32_t)f2bf_rne(a[3]) << 16);
    ((uint2*)xb)[i] = o;
  }
}

// ---------- kernel 1: T1[64][4096] = core0(64x64) @ core1(64x4096) ----------
__global__ __launch_bounds__(256) void k_t1(const float* __restrict__ c0, const float* __restrict__ c1,
                                            float* __restrict__ T1) {
  const int col = blockIdx.x * 256 + threadIdx.x;  // [0,4096)
  const int row = blockIdx.y;                      // [0,64)
  float acc = 0.f;
#pragma unroll 16
  for (int r = 0; r < 64; ++r) acc += c0[row * 64 + r] * c1[(size_t)r * 4096 + col];
  T1[(size_t)row * 4096 + col] = acc;
}

// ---------- kernel 2: T2[4096][4096] = T1r(4096x64) @ core2(64x4096) ----------
__global__ __launch_bounds__(256) void k_t2(const float* __restrict__ T1, const float* __restrict__ c2,
                                            float* __restrict__ T2) {
  __shared__ float t1s[16][64];
  const int tid = threadIdx.x;
  const int rowbase = blockIdx.y * 16;
  for (int idx = tid; idx < 1024; idx += 256)
    t1s[idx >> 6][idx & 63] = T1[(size_t)(rowbase + (idx >> 6)) * 64 + (idx & 63)];
  __syncthreads();
  const int col = blockIdx.x * 256 + tid;  // [0,4096)
  float acc[16];
#pragma unroll
  for (int j = 0; j < 16; ++j) acc[j] = 0.f;
  for (int r = 0; r < 64; ++r) {
    float b = c2[(size_t)r * 4096 + col];
#pragma unroll
    for (int j = 0; j < 16; ++j) acc[j] += t1s[j][r] * b;
  }
#pragma unroll
  for (int j = 0; j < 16; ++j) T2[(size_t)(rowbase + j) * 4096 + col] = acc[j];
}

// ---------- kernel 3: per row12, M = T2row(64x64) @ c3(64x64), coalesced Wb writes ----------
// W[obase + o3*8+o4][ibase + i3*8+i4] = sum_r3 T2[row12][(i3*8+o3)*64 + r3] * c3[r3][i4*8+o4]
__global__ __launch_bounds__(256) void k_w(const float* __restrict__ T2, const float* __restrict__ c3,
                                           u16* __restrict__ Wb) {
  __shared__ float t2p[64 * 65];  // [io3][r3] padded to 65: bank = (row+r3)%32 -> 2-way max (free)
  __shared__ float c3s[64 * 64];
  const int tid = threadIdx.x;
  const int row12 = blockIdx.x;  // (i1o1)*64 + (i2o2)
  for (int idx = tid; idx < 4096; idx += 256) {
    t2p[(idx >> 6) * 65 + (idx & 63)] = T2[(size_t)row12 * 4096 + idx];
    c3s[idx] = c3[idx];
  }
  __syncthreads();
  const int orow = tid >> 2;        // o3*8+o4 in [0,64)
  const int o3 = orow >> 3, o4 = orow & 7;
  const int ib16 = (tid & 3) * 16;  // i-block of 16
  float acc[16];
#pragma unroll
  for (int c = 0; c < 16; ++c) acc[c] = 0.f;
  for (int r3 = 0; r3 < 64; ++r3) {
#pragma unroll
    for (int c = 0; c < 16; ++c) {
      const int i = ib16 + c;
      acc[c] += t2p[((i >> 3) * 8 + o3) * 65 + r3] * c3s[r3 * 64 + (i & 7) * 8 + o4];
    }
  }
  const int i1o1 = row12 >> 6, i2o2 = row12 & 63;
  const int obase = ((i1o1 & 7) << 9) | ((i2o2 & 7) << 6);
  const int ibase = ((i1o1 >> 3) << 9) | ((i2o2 >> 3) << 6);
  uint32_t pk[8];
#pragma unroll
  for (int c = 0; c < 8; ++c)
    pk[c] = (uint32_t)f2bf_rne(acc[2 * c]) | ((uint32_t)f2bf_rne(acc[2 * c + 1]) << 16);
  uint4* dst = (uint4*)&Wb[(size_t)(obase + orow) * 4096 + ibase + ib16];
  dst[0] = make_uint4(pk[0], pk[1], pk[2], pk[3]);
  dst[1] = make_uint4(pk[4], pk[5], pk[6], pk[7]);
}

// ---------- kernel 4: out(16384x4096) = Xb @ Wb^T + bias ----------
// 256x256 tile, 8 waves (2Mx4N), BK=32, triple-buffered LDS, counted vmcnt(4),
// XOR-swizzled LDS (write side via pre-swizzled global source), setprio around MFMA.
__global__ __launch_bounds__(512, 2) void k_gemm(const u16* __restrict__ Xb, const u16* __restrict__ Wb,
                                                 const float* __restrict__ bias, float* __restrict__ out) {
  __shared__ alignas(16) u16 Abuf[3][256 * 32];  // 48 KiB
  __shared__ alignas(16) u16 Bbuf[3][256 * 32];  // 48 KiB
  const int tid = threadIdx.x;
  const int wid = tid >> 6, l = tid & 63;
  const int bm = blockIdx.x;  // 0..63
  const int bn = blockIdx.y;  // 0..15
  const int wm = wid >> 2, wn = wid & 3;

  // --- staging (write) addressing: LDS dest linear, global source pre-swizzled ---
  // lane l of wave wid, round r covers LDS row = r*128 + wid*16 + (l>>2), 16B slot (l&3).
  // element for that slot is global k-chunk (l&3) ^ ((l>>3)&3)  [rows' bits1-2 = (l>>3)&3]
  const int ach = (l & 3) ^ ((l >> 3) & 3);
  const size_t ag0 = (size_t)(bm * 256 + wid * 16 + (l >> 2)) * K_DIM + ach * 8;
  const size_t ag1 = ag0 + (size_t)128 * K_DIM;
  const size_t bg0 = (size_t)(bn * 256 + wid * 16 + (l >> 2)) * K_DIM + ach * 8;
  const size_t bg1 = bg0 + (size_t)128 * K_DIM;
  const int lst0 = (wid * 16) * 32;        // lds elem offset, round 0 (wave-uniform)
  const int lst1 = (128 + wid * 16) * 32;  // round 1

  // --- read addressing: row = ...+(l&15), k-chunk (l>>4) swizzled by rows' bits1-2 ---
  const int rsw = ((l >> 4) ^ ((l >> 1) & 3)) * 8;  // swizzled k-elem offset in row
  const int arow0 = wm * 128 + (l & 15);
  const int brow0 = wn * 64 + (l & 15);

  f32x4 acc[8][4];
#pragma unroll
  for (int m = 0; m < 8; ++m)
#pragma unroll
    for (int n = 0; n < 4; ++n) acc[m][n] = (f32x4){0.f, 0.f, 0.f, 0.f};

#define GSTAGE(T, SB) do {                                  \
    const int ko_ = (T) * 32;                               \
    gld_lds16(Xb + ag0 + ko_, &Abuf[SB][lst0]);             \
    gld_lds16(Xb + ag1 + ko_, &Abuf[SB][lst1]);             \
    gld_lds16(Wb + bg0 + ko_, &Bbuf[SB][lst0]);             \
    gld_lds16(Wb + bg1 + ko_, &Bbuf[SB][lst1]);             \
  } while (0)

#define COMPUTE(B) do {                                                                   \
    bf16x8 af[8], bfr[4];                                                                 \
    _Pragma("unroll")                                                                     \
    for (int m = 0; m < 8; ++m) af[m] = *(const bf16x8*)&Abuf[B][(arow0 + m * 16) * 32 + rsw]; \
    _Pragma("unroll")                                                                     \
    for (int n = 0; n < 4; ++n) bfr[n] = *(const bf16x8*)&Bbuf[B][(brow0 + n * 16) * 32 + rsw]; \
    __builtin_amdgcn_s_setprio(1);                                                        \
    _Pragma("unroll")                                                                     \
    for (int m = 0; m < 8; ++m)                                                           \
      _Pragma("unroll")                                                                   \
      for (int n = 0; n < 4; ++n)                                                         \
        acc[m][n] = __builtin_amdgcn_mfma_f32_16x16x32_bf16(af[m], bfr[n], acc[m][n], 0, 0, 0); \
    __builtin_amdgcn_s_setprio(0);                                                        \
  } while (0)

#define BOUNDARY4 do { asm volatile("s_waitcnt vmcnt(4)" ::: "memory"); \
    __builtin_amdgcn_s_barrier(); asm volatile("" ::: "memory"); } while (0)
#define BOUNDARY0 do { asm volatile("s_waitcnt vmcnt(0)" ::: "memory"); \
    __builtin_amdgcn_s_barrier(); asm volatile("" ::: "memory"); } while (0)

  // prologue: tiles 0,1 staged; wait for tile 0 (8 outstanding -> 4)
  GSTAGE(0, 0);
  GSTAGE(1, 1);
  BOUNDARY4;

  // steady state: 42 triples cover tiles 0..125, staging tiles 2..127.
  // invariant at each BOUNDARY4: 8 gld outstanding -> completes next tile's 4.
#pragma unroll 1
  for (int t3 = 0; t3 < 126; t3 += 3) {
    GSTAGE(t3 + 2, 2); COMPUTE(0); BOUNDARY4;
    GSTAGE(t3 + 3, 0); COMPUTE(1); BOUNDARY4;
    GSTAGE(t3 + 4, 1); COMPUTE(2); BOUNDARY4;
  }
  // tail: tile 126 (buf0) then drain stage(127), tile 127 (buf1)
  COMPUTE(0);
  BOUNDARY0;
  COMPUTE(1);

  // epilogue: C/D mapping col=lane&15, row=(lane>>4)*4+j
  const int orow_base = bm * 256 + wm * 128 + (l >> 4) * 4;
  const int ocol_base = bn * 256 + wn * 64 + (l & 15);
#pragma unroll
  for (int n = 0; n < 4; ++n) {
    const int oc = ocol_base + n * 16;
    const float bv = bias[oc];
#pragma unroll
    for (int m = 0; m < 8; ++m) {
      const int orb = orow_base + m * 16;
#pragma unroll
      for (int j = 0; j < 4; ++j)
        out[(size_t)(orb + j) * 4096 + oc] = acc[m][n][j] + bv;
    }
  }
#undef GSTAGE
#undef COMPUTE
#undef BOUNDARY4
#undef BOUNDARY0
}

extern "C" void kernel_launch(void* const* d_in, const int* in_sizes, int n_in,
                              void* d_out, int out_size, void* d_ws, size_t ws_size,
                              hipStream_t stream) {
  const float* x    = (const float*)d_in[0];
  const float* c0   = (const float*)d_in[1];
  const float* c1   = (const float*)d_in[2];
  const float* c2   = (const float*)d_in[3];
  const float* c3   = (const float*)d_in[4];
  const float* bias = (const float*)d_in[5];
  float* out = (float*)d_out;

  char* ws = (char*)d_ws;
  float* T1 = (float*)ws;                                          //  1 MiB: 64*4096 f32
  float* T2 = (float*)(ws + (1u << 20));                           // 64 MiB: 4096*4096 f32
  u16*   Wb = (u16*)(ws + (1u << 20) + (64u << 20));               // 32 MiB: 4096*4096 bf16
  u16*   Xb = (u16*)(ws + (1u << 20) + (64u << 20) + (32u << 20)); // 128 MiB: 16384*4096 bf16

  hipLaunchKernelGGL(k_cvt_x, dim3(2048), dim3(256), 0, stream, x, Xb, 16777216);
  hipLaunchKernelGGL(k_t1,    dim3(16, 64), dim3(256), 0, stream, c0, c1, T1);
  hipLaunchKernelGGL(k_t2,    dim3(16, 256), dim3(256), 0, stream, T1, c2, T2);
  hipLaunchKernelGGL(k_w,     dim3(4096), dim3(256), 0, stream, T2, c3, Wb);
  hipLaunchKernelGGL(k_gemm,  dim3(64, 16), dim3(512), 0, stream, Xb, Wb, bias, out);
}

// Round 7
// 1019.716 us; speedup vs baseline: 1.3515x; 1.0441x over previous
//
#include <hip/hip_runtime.h>
#include <hip/hip_bf16.h>
#include <stdint.h>

typedef unsigned short u16;
typedef __attribute__((ext_vector_type(4))) float f32x4;
typedef __attribute__((ext_vector_type(8))) __bf16 bf16x8;

#define K_DIM 4096

// ---------- helpers ----------
__device__ __forceinline__ u16 f2bf_rne(float f) {
  union { float f; uint32_t u; } v; v.f = f;
  uint32_t u = v.u;
  return (u16)((u + 0x7fffu + ((u >> 16) & 1u)) >> 16);
}

__device__ __forceinline__ void gld_lds16(const u16* g, u16* l) {
  __builtin_amdgcn_global_load_lds((const __attribute__((address_space(1))) void*)g,
                                   (__attribute__((address_space(3))) void*)l,
                                   16, 0, 0);
}

// ---------- kernel 0: x (fp32) -> Xb (bf16) ----------
__global__ __launch_bounds__(256) void k_cvt_x(const float* __restrict__ x, u16* __restrict__ xb, int n4) {
  const int stride = gridDim.x * 256;
  for (int i = blockIdx.x * 256 + threadIdx.x; i < n4; i += stride) {
    f32x4 a = ((const f32x4*)x)[i];
    uint2 o;
    o.x = (uint32_t)f2bf_rne(a[0]) | ((uint32_t)f2bf_rne(a[1]) << 16);
    o.y = (uint32_t)f2bf_rne(a[2]) | ((uint32_t)f2bf_rne(a[3]) << 16);
    ((uint2*)xb)[i] = o;
  }
}

// ---------- kernel 1: T1[64][4096] = core0(64x64) @ core1(64x4096) ----------
__global__ __launch_bounds__(256) void k_t1(const float* __restrict__ c0, const float* __restrict__ c1,
                                            float* __restrict__ T1) {
  const int col = blockIdx.x * 256 + threadIdx.x;
  const int row = blockIdx.y;
  float acc = 0.f;
#pragma unroll 16
  for (int r = 0; r < 64; ++r) acc += c0[row * 64 + r] * c1[(size_t)r * 4096 + col];
  T1[(size_t)row * 4096 + col] = acc;
}

// ---------- kernel 2: T2[4096][4096] = T1r(4096x64) @ core2(64x4096) ----------
__global__ __launch_bounds__(256) void k_t2(const float* __restrict__ T1, const float* __restrict__ c2,
                                            float* __restrict__ T2) {
  __shared__ float t1s[16][64];
  const int tid = threadIdx.x;
  const int rowbase = blockIdx.y * 16;
  for (int idx = tid; idx < 1024; idx += 256)
    t1s[idx >> 6][idx & 63] = T1[(size_t)(rowbase + (idx >> 6)) * 64 + (idx & 63)];
  __syncthreads();
  const int col = blockIdx.x * 256 + tid;
  float acc[16];
#pragma unroll
  for (int j = 0; j < 16; ++j) acc[j] = 0.f;
  for (int r = 0; r < 64; ++r) {
    float b = c2[(size_t)r * 4096 + col];
#pragma unroll
    for (int j = 0; j < 16; ++j) acc[j] += t1s[j][r] * b;
  }
#pragma unroll
  for (int j = 0; j < 16; ++j) T2[(size_t)(rowbase + j) * 4096 + col] = acc[j];
}

// ---------- kernel 3: per row12, M = T2row(64x64) @ c3(64x64), transposed-c3 vector reads ----------
__global__ __launch_bounds__(256) void k_w(const float* __restrict__ T2, const float* __restrict__ c3,
                                           u16* __restrict__ Wb) {
  __shared__ float t2p[64 * 65];   // [io3][r3], pad 65: bank=(row+r3)%32 -> 2-way max (free)
  __shared__ float c3t[64 * 64];   // [r3][o4*8 + i4]  (transposed inner dims)
  const int tid = threadIdx.x;
  const int row12 = blockIdx.x;
  for (int idx = tid; idx < 4096; idx += 256) {
    t2p[(idx >> 6) * 65 + (idx & 63)] = T2[(size_t)row12 * 4096 + idx];
    const int r3 = idx >> 6, orow = idx & 63;  // orow = i4*8 + o4
    c3t[r3 * 64 + ((orow & 7) << 3) + (orow >> 3)] = c3[idx];
  }
  __syncthreads();
  const int orow = tid >> 2;        // o3*8+o4
  const int o3 = orow >> 3, o4 = orow & 7;
  const int ib16 = (tid & 3) * 16;
  const int rowA = ((ib16 >> 3)) * 8 + o3;      // t2p row for c=0..7
  const int rowB = ((ib16 >> 3) + 1) * 8 + o3;  // for c=8..15
  float acc[16];
#pragma unroll
  for (int c = 0; c < 16; ++c) acc[c] = 0.f;
  for (int r3 = 0; r3 < 64; ++r3) {
    const float ta = t2p[rowA * 65 + r3];
    const float tb = t2p[rowB * 65 + r3];
    const float* cv = &c3t[r3 * 64 + o4 * 8];
    f32x4 c0v = *(const f32x4*)cv;
    f32x4 c1v = *(const f32x4*)(cv + 4);
#pragma unroll
    for (int j = 0; j < 4; ++j) {
      acc[j]      += ta * c0v[j];
      acc[4 + j]  += ta * c1v[j];
      acc[8 + j]  += tb * c0v[j];
      acc[12 + j] += tb * c1v[j];
    }
  }
  const int i1o1 = row12 >> 6, i2o2 = row12 & 63;
  const int obase = ((i1o1 & 7) << 9) | ((i2o2 & 7) << 6);
  const int ibase = ((i1o1 >> 3) << 9) | ((i2o2 >> 3) << 6);
  uint32_t pk[8];
#pragma unroll
  for (int c = 0; c < 8; ++c)
    pk[c] = (uint32_t)f2bf_rne(acc[2 * c]) | ((uint32_t)f2bf_rne(acc[2 * c + 1]) << 16);
  uint4* dst = (uint4*)&Wb[(size_t)(obase + orow) * 4096 + ibase + ib16];
  dst[0] = make_uint4(pk[0], pk[1], pk[2], pk[3]);
  dst[1] = make_uint4(pk[4], pk[5], pk[6], pk[7]);
}

// ---------- kernel 4: out(16384x4096) = Xb @ Wb^T + bias ----------
// 256x256 tile, 8 waves (2Mx4N), BK=64, 2-deep LDS dbuf (128 KiB), 4 phases/K-tile.
// Each phase: {frag ds_reads | 1 staging set (2 gld) -> bar -> lgkm -> setprio+16 MFMA
//              -> counted vmcnt(4) -> bar}.  vmcnt BEFORE the barrier (all waves' staged
// writes retired before any wave reads them next phase) — never vmcnt(0) in steady state.
// XOR-swizzled LDS: write via pre-swizzled global source, read chunk ^= row&7.
__global__ __launch_bounds__(512, 2) void k_gemm(const u16* __restrict__ Xb, const u16* __restrict__ Wb,
                                                 const float* __restrict__ bias, float* __restrict__ out) {
  __shared__ alignas(16) u16 Abuf[2][256 * 64];  // 64 KiB
  __shared__ alignas(16) u16 Bbuf[2][256 * 64];  // 64 KiB
  const int tid = threadIdx.x;
  const int wid = tid >> 6, l = tid & 63;
  const int bm = blockIdx.x;  // 0..63
  const int bn = blockIdx.y;  // 0..15
  const int wm = wid >> 2, wn = wid & 3;

  // --- staging (write): LDS linear, global chunk pre-swizzled: chunk = (l&7)^((l>>3)&7) ---
  const int sch = (l & 7) ^ ((l >> 3) & 7);
  const int arow_g = 8 * wid + (l >> 3);                         // A row within 64-row group
  const int brow_g = (wid >> 2) * 64 + 8 * (wid & 3) + (l >> 3); // B row within stripe pattern
  const u16* AgBase = Xb + (size_t)(bm * 256) * K_DIM + sch * 8;
  const u16* BgBase = Wb + (size_t)(bn * 256) * K_DIM + sch * 8;
  const int aldsw = (8 * wid) * 64;                              // wave-uniform LDS elem base
  const int bldsw = ((wid >> 2) * 64 + 8 * (wid & 3)) * 64;

  // --- read: row&7 == l&7 (all row bases are multiples of 16) -> lane-constant swizzle ---
  const int kc0 = (((l >> 4)) ^ (l & 7)) * 8;       // k-half 0 chunk, swizzled, in elems
  const int kc1 = ((4 + (l >> 4)) ^ (l & 7)) * 8;   // k-half 1
  const int aoff = (wm * 128 + (l & 15)) * 64;
  const int boff = (wn * 64 + (l & 15)) * 64;

  f32x4 acc[8][4];
#pragma unroll
  for (int m = 0; m < 8; ++m)
#pragma unroll
    for (int n = 0; n < 4; ++n) acc[m][n] = (f32x4){0.f, 0.f, 0.f, 0.f};

  bf16x8 a[4][2], b0[2][2], b1[2][2];

#define STAGE_A(T, S, PB) do { const size_t ko_ = (size_t)(T) * 64;                                  \
    gld_lds16(AgBase + (size_t)((S) * 64 + arow_g) * K_DIM + ko_,        &Abuf[PB][(S) * 4096 + aldsw]);        \
    gld_lds16(AgBase + (size_t)(128 + (S) * 64 + arow_g) * K_DIM + ko_,  &Abuf[PB][8192 + (S) * 4096 + aldsw]); \
  } while (0)
#define STAGE_B(T, S, PB) do { const size_t ko_ = (size_t)(T) * 64;                                  \
    gld_lds16(BgBase + (size_t)((S) * 32 + brow_g) * K_DIM + ko_,        &Bbuf[PB][(S) * 2048 + bldsw]);        \
    gld_lds16(BgBase + (size_t)(128 + (S) * 32 + brow_g) * K_DIM + ko_,  &Bbuf[PB][8192 + (S) * 2048 + bldsw]); \
  } while (0)

#define LDA(P, MH) do { _Pragma("unroll") for (int mt = 0; mt < 4; ++mt) {       \
    a[mt][0] = *(const bf16x8*)&Abuf[P][aoff + (MH) * 4096 + mt * 1024 + kc0];   \
    a[mt][1] = *(const bf16x8*)&Abuf[P][aoff + (MH) * 4096 + mt * 1024 + kc1]; } } while (0)
#define LDB(BV, P, NH) do { _Pragma("unroll") for (int nt = 0; nt < 2; ++nt) {   \
    BV[nt][0] = *(const bf16x8*)&Bbuf[P][boff + (NH) * 2048 + nt * 1024 + kc0];  \
    BV[nt][1] = *(const bf16x8*)&Bbuf[P][boff + (NH) * 2048 + nt * 1024 + kc1]; } } while (0)

#define MM(MB, NB, BV) do { __builtin_amdgcn_s_setprio(1);                                            \
    _Pragma("unroll") for (int mt = 0; mt < 4; ++mt)                                                  \
    _Pragma("unroll") for (int nt = 0; nt < 2; ++nt) {                                                \
      acc[(MB)+mt][(NB)+nt] = __builtin_amdgcn_mfma_f32_16x16x32_bf16(a[mt][0], BV[nt][0], acc[(MB)+mt][(NB)+nt], 0, 0, 0); \
      acc[(MB)+mt][(NB)+nt] = __builtin_amdgcn_mfma_f32_16x16x32_bf16(a[mt][1], BV[nt][1], acc[(MB)+mt][(NB)+nt], 0, 0, 0); } \
    __builtin_amdgcn_s_setprio(0); } while (0)

#define FENCE asm volatile("" ::: "memory")
#define BAR do { FENCE; __builtin_amdgcn_s_barrier(); FENCE; } while (0)
#define VMW4 asm volatile("s_waitcnt vmcnt(4)" ::: "memory")
#define VMW2 asm volatile("s_waitcnt vmcnt(2)" ::: "memory")
#define VMW0 asm volatile("s_waitcnt vmcnt(0)" ::: "memory")
#define LGKM asm volatile("s_waitcnt lgkmcnt(0)" ::: "memory")

// Per-wave ledger (2 loads/set; stage order A0,B0,B1,A1, one set per phase):
// invariant entering tile T: outstanding = {B1(T),A1(T)} = 4; A0(T),B0(T) retired + barrier'd.
// ph0: reads A0,B0; stages A0(T+1) -> 6; end VMW4 retires B1(T)   (read next phase)
// ph1: reads B1;    stages B0(T+1) -> 6; end VMW4 retires A1(T)
// ph2: reads A1;    stages B1(T+1) -> 6; end VMW4 retires A0(T+1)
// ph3: (regs only); stages A1(T+1) -> 6; end VMW4 retires B0(T+1) -> invariant for T+1.
#define TILE(T, P) do {                                                                          \
    LDA(P, 0); LDB(b0, P, 0); STAGE_A((T) + 1, 0, (P) ^ 1); BAR; LGKM; MM(0, 0, b0); VMW4; BAR;  \
    LDB(b1, P, 1);            STAGE_B((T) + 1, 0, (P) ^ 1); BAR; LGKM; MM(0, 2, b1); VMW4; BAR;  \
    LDA(P, 1);                STAGE_B((T) + 1, 1, (P) ^ 1); BAR; LGKM; MM(4, 2, b1); VMW4; BAR;  \
                              STAGE_A((T) + 1, 1, (P) ^ 1); BAR;       MM(4, 0, b0); VMW4; BAR;  \
  } while (0)

  // prologue: stage tile 0 (A0,B0,B1,A1) -> 8 outstanding; retire A0,B0; barrier.
  STAGE_A(0, 0, 0); STAGE_B(0, 0, 0); STAGE_B(0, 1, 0); STAGE_A(0, 1, 0);
  VMW4; BAR;

#pragma unroll 1
  for (int t = 0; t < 62; t += 2) {
    TILE(t, 0);
    TILE(t + 1, 1);
  }
  TILE(62, 0);  // stages tile 63 into buf1

  // tail tile 63 (parity 1), nothing staged; drain 4 -> 2 -> 0.
  LDA(1, 0); LDB(b0, 1, 0); BAR; LGKM; MM(0, 0, b0); VMW2; BAR;
  LDB(b1, 1, 1);            BAR; LGKM; MM(0, 2, b1); VMW0; BAR;
  LDA(1, 1);                BAR; LGKM; MM(4, 2, b1); BAR;
                                       MM(4, 0, b0);

  // epilogue: C/D mapping col=lane&15, row=(lane>>4)*4+j
  const int orow_base = bm * 256 + wm * 128 + (l >> 4) * 4;
  const int ocol_base = bn * 256 + wn * 64 + (l & 15);
#pragma unroll
  for (int n = 0; n < 4; ++n) {
    const int oc = ocol_base + n * 16;
    const float bv = bias[oc];
#pragma unroll
    for (int m = 0; m < 8; ++m) {
      const int orb = orow_base + m * 16;
#pragma unroll
      for (int j = 0; j < 4; ++j)
        out[(size_t)(orb + j) * 4096 + oc] = acc[m][n][j] + bv;
    }
  }
#undef STAGE_A
#undef STAGE_B
#undef LDA
#undef LDB
#undef MM
#undef FENCE
#undef BAR
#undef VMW4
#undef VMW2
#undef VMW0
#undef LGKM
#undef TILE
}

extern "C" void kernel_launch(void* const* d_in, const int* in_sizes, int n_in,
                              void* d_out, int out_size, void* d_ws, size_t ws_size,
                              hipStream_t stream) {
  const float* x    = (const float*)d_in[0];
  const float* c0   = (const float*)d_in[1];
  const float* c1   = (const float*)d_in[2];
  const float* c2   = (const float*)d_in[3];
  const float* c3   = (const float*)d_in[4];
  const float* bias = (const float*)d_in[5];
  float* out = (float*)d_out;

  char* ws = (char*)d_ws;
  float* T1 = (float*)ws;                                          //  1 MiB: 64*4096 f32
  float* T2 = (float*)(ws + (1u << 20));                           // 64 MiB: 4096*4096 f32
  u16*   Wb = (u16*)(ws + (1u << 20) + (64u << 20));               // 32 MiB: 4096*4096 bf16
  u16*   Xb = (u16*)(ws + (1u << 20) + (64u << 20) + (32u << 20)); // 128 MiB: 16384*4096 bf16

  hipLaunchKernelGGL(k_cvt_x, dim3(2048), dim3(256), 0, stream, x, Xb, 16777216);
  hipLaunchKernelGGL(k_t1,    dim3(16, 64), dim3(256), 0, stream, c0, c1, T1);
  hipLaunchKernelGGL(k_t2,    dim3(16, 256), dim3(256), 0, stream, T1, c2, T2);
  hipLaunchKernelGGL(k_w,     dim3(4096), dim3(256), 0, stream, T2, c3, Wb);
  hipLaunchKernelGGL(k_gemm,  dim3(64, 16), dim3(512), 0, stream, Xb, Wb, bias, out);
}